// Round 1
// baseline (5261.646 us; speedup 1.0000x reference)
//
#include <hip/hip_runtime.h>
#include <math.h>

constexpr int kE    = 384;    // embed dim
constexpr int kT    = 16;     // tokens per window (4x4)
constexpr int kHD   = 32;     // head dim
constexpr int kNTok = 4096;   // tokens per batch (64x64)
constexpr int kNWin = 8192;   // 32 * 16 * 16 windows

__global__ __launch_bounds__(256, 1)
void win_attn_f32(const float* __restrict__ x,
                  const float* __restrict__ w_in,
                  const float* __restrict__ b_in,
                  const float* __restrict__ w_out,
                  const float* __restrict__ b_out,
                  float* __restrict__ out)
{
    // 96 KB LDS total -> 1 block/CU
    __shared__ float xs[kE][kT];   // x^T [k][t]; later reused as attn-out^T
    __shared__ float qs[kT][kE];   // q (pre-scaled)
    __shared__ float ks[kT][kE];
    __shared__ float vs[kT][kE];

    const int tid = threadIdx.x;
    const int wid = blockIdx.x;
    const int bb  = wid >> 8;          // batch
    const int wh  = (wid >> 4) & 15;   // window row
    const int ww  = wid & 15;          // window col

    // ---------- load x window, transposed into xs[k][t] ----------
    {
        const int t = tid >> 4;        // token 0..15
        const int g = tid & 15;        // lane-in-token
        const int r = t >> 2, c = t & 3;
        const int n = (wh*4 + r)*64 + (ww*4 + c);
        const float4* xrow = (const float4*)(x + ((size_t)bb*kNTok + n)*kE);
        #pragma unroll
        for (int i = 0; i < 6; ++i) {
            float4 v4 = xrow[g + i*16];
            const int k0 = (g + i*16)*4;
            xs[k0+0][t] = v4.x; xs[k0+1][t] = v4.y;
            xs[k0+2][t] = v4.z; xs[k0+3][t] = v4.w;
        }
    }
    __syncthreads();

    const float scale = 0.17677669529663687f;  // 1/sqrt(32)

    // store one qkv output column e (all 16 tokens) to the right buffer
    auto qkv_store = [&](int e, const float* acc, float bias) {
        if (e < kE) {
            #pragma unroll
            for (int t = 0; t < kT; ++t) qs[t][e] = (acc[t] + bias) * scale;
        } else if (e < 2*kE) {
            #pragma unroll
            for (int t = 0; t < kT; ++t) ks[t][e - kE] = acc[t] + bias;
        } else {
            #pragma unroll
            for (int t = 0; t < kT; ++t) vs[t][e - 2*kE] = acc[t] + bias;
        }
    };

    // dual-column QKV GEMM: qkv[t][e] = sum_k x[t][k] * w_in[e][k]
    auto qkv2 = [&](int e0, int e1) {
        float acc0[kT], acc1[kT];
        #pragma unroll
        for (int t = 0; t < kT; ++t) { acc0[t] = 0.f; acc1[t] = 0.f; }
        const float4* w0 = (const float4*)(w_in + (size_t)e0*kE);
        const float4* w1 = (const float4*)(w_in + (size_t)e1*kE);
        for (int k4 = 0; k4 < kE/4; ++k4) {
            const float4 wa = w0[k4];
            const float4 wb = w1[k4];
            #pragma unroll
            for (int j = 0; j < 4; ++j) {
                const int k = k4*4 + j;
                float xt[kT];
                *(float4*)&xt[0]  = *(const float4*)&xs[k][0];
                *(float4*)&xt[4]  = *(const float4*)&xs[k][4];
                *(float4*)&xt[8]  = *(const float4*)&xs[k][8];
                *(float4*)&xt[12] = *(const float4*)&xs[k][12];
                const float wav = (j==0)?wa.x:(j==1)?wa.y:(j==2)?wa.z:wa.w;
                const float wbv = (j==0)?wb.x:(j==1)?wb.y:(j==2)?wb.z:wb.w;
                #pragma unroll
                for (int t = 0; t < kT; ++t) {
                    acc0[t] = fmaf(wav, xt[t], acc0[t]);
                    acc1[t] = fmaf(wbv, xt[t], acc1[t]);
                }
            }
        }
        qkv_store(e0, acc0, b_in[e0]);
        qkv_store(e1, acc1, b_in[e1]);
    };

    auto qkv1 = [&](int e0) {
        float acc0[kT];
        #pragma unroll
        for (int t = 0; t < kT; ++t) acc0[t] = 0.f;
        const float4* w0 = (const float4*)(w_in + (size_t)e0*kE);
        for (int k4 = 0; k4 < kE/4; ++k4) {
            const float4 wa = w0[k4];
            #pragma unroll
            for (int j = 0; j < 4; ++j) {
                const int k = k4*4 + j;
                float xt[kT];
                *(float4*)&xt[0]  = *(const float4*)&xs[k][0];
                *(float4*)&xt[4]  = *(const float4*)&xs[k][4];
                *(float4*)&xt[8]  = *(const float4*)&xs[k][8];
                *(float4*)&xt[12] = *(const float4*)&xs[k][12];
                const float wav = (j==0)?wa.x:(j==1)?wa.y:(j==2)?wa.z:wa.w;
                #pragma unroll
                for (int t = 0; t < kT; ++t)
                    acc0[t] = fmaf(wav, xt[t], acc0[t]);
            }
        }
        qkv_store(e0, acc0, b_in[e0]);
    };

    // e coverage: [0,1024) via two dual passes on all threads,
    // [1024,1152) leftover on the upper half (lower half gets extra out_proj work)
    qkv2(tid, tid + 256);
    qkv2(tid + 512, tid + 768);
    if (tid >= 128) qkv1(1024 + (tid - 128));
    __syncthreads();

    // ---------- attention: thread = (head, query-row), 192 active ----------
    if (tid < 192) {
        const int h  = tid >> 4;
        const int tq = tid & 15;
        float qreg[kHD];
        {
            const float4* qrow = (const float4*)(&qs[tq][h*kHD]);
            #pragma unroll
            for (int i = 0; i < 8; ++i) ((float4*)qreg)[i] = qrow[i];
        }
        float s[kT];
        #pragma unroll
        for (int tk = 0; tk < kT; ++tk) {
            const float4* krow = (const float4*)(&ks[tk][h*kHD]);
            float acc = 0.f;
            #pragma unroll
            for (int i = 0; i < 8; ++i) {
                const float4 kv = krow[i];
                acc = fmaf(qreg[4*i+0], kv.x, acc);
                acc = fmaf(qreg[4*i+1], kv.y, acc);
                acc = fmaf(qreg[4*i+2], kv.z, acc);
                acc = fmaf(qreg[4*i+3], kv.w, acc);
            }
            s[tk] = acc;
        }
        float m = s[0];
        #pragma unroll
        for (int tk = 1; tk < kT; ++tk) m = fmaxf(m, s[tk]);
        float sum = 0.f;
        #pragma unroll
        for (int tk = 0; tk < kT; ++tk) { s[tk] = __expf(s[tk] - m); sum += s[tk]; }
        const float inv = 1.f / sum;

        float o[kHD];
        #pragma unroll
        for (int d = 0; d < kHD; ++d) o[d] = 0.f;
        #pragma unroll
        for (int tk = 0; tk < kT; ++tk) {
            const float p = s[tk] * inv;
            const float4* vrow = (const float4*)(&vs[tk][h*kHD]);
            #pragma unroll
            for (int i = 0; i < 8; ++i) {
                const float4 vv = vrow[i];
                o[4*i+0] = fmaf(p, vv.x, o[4*i+0]);
                o[4*i+1] = fmaf(p, vv.y, o[4*i+1]);
                o[4*i+2] = fmaf(p, vv.z, o[4*i+2]);
                o[4*i+3] = fmaf(p, vv.w, o[4*i+3]);
            }
        }
        // write attn output transposed into xs[k][t] (xs reads all completed)
        #pragma unroll
        for (int d = 0; d < kHD; ++d) xs[h*kHD + d][tq] = o[d];
    }
    __syncthreads();

    // ---------- out_proj: out[t][e2] = sum_k att[t][k] * w_out[e2][k] ----------
    auto oproj = [&](int e2a, int e2b, bool dual) {
        float acc0[kT], acc1[kT];
        #pragma unroll
        for (int t = 0; t < kT; ++t) { acc0[t] = 0.f; acc1[t] = 0.f; }
        const float4* w0 = (const float4*)(w_out + (size_t)e2a*kE);
        const float4* w1 = (const float4*)(w_out + (size_t)e2b*kE);
        for (int k4 = 0; k4 < kE/4; ++k4) {
            const float4 wa = w0[k4];
            const float4 wb = dual ? w1[k4] : make_float4(0,0,0,0);
            #pragma unroll
            for (int j = 0; j < 4; ++j) {
                const int k = k4*4 + j;
                float xt[kT];
                *(float4*)&xt[0]  = *(const float4*)&xs[k][0];
                *(float4*)&xt[4]  = *(const float4*)&xs[k][4];
                *(float4*)&xt[8]  = *(const float4*)&xs[k][8];
                *(float4*)&xt[12] = *(const float4*)&xs[k][12];
                const float wav = (j==0)?wa.x:(j==1)?wa.y:(j==2)?wa.z:wa.w;
                const float wbv = (j==0)?wb.x:(j==1)?wb.y:(j==2)?wb.z:wb.w;
                #pragma unroll
                for (int t = 0; t < kT; ++t) {
                    acc0[t] = fmaf(wav, xt[t], acc0[t]);
                    if (dual) acc1[t] = fmaf(wbv, xt[t], acc1[t]);
                }
            }
        }
        const float bo0 = b_out[e2a];
        const float bo1 = dual ? b_out[e2b] : 0.f;
        #pragma unroll
        for (int t = 0; t < kT; ++t) {
            const int r = t >> 2, c = t & 3;
            const int n = (wh*4 + r)*64 + (ww*4 + c);
            float* orow = out + ((size_t)bb*kNTok + n)*kE;
            orow[e2a] = acc0[t] + bo0;
            if (dual) orow[e2b] = acc1[t] + bo1;
        }
    };

    // e2 coverage: lower half threads do {tid, tid+256}, upper half do {tid}
    if (tid < 128) oproj(tid, tid + 256, true);
    else           oproj(tid, tid, false);
}

extern "C" void kernel_launch(void* const* d_in, const int* in_sizes, int n_in,
                              void* d_out, int out_size, void* d_ws, size_t ws_size,
                              hipStream_t stream) {
    const float* x     = (const float*)d_in[0];
    const float* w_in  = (const float*)d_in[1];
    const float* b_in  = (const float*)d_in[2];
    const float* w_out = (const float*)d_in[3];
    const float* b_out = (const float*)d_in[4];
    float* out = (float*)d_out;
    win_attn_f32<<<dim3(kNWin), dim3(256), 0, stream>>>(x, w_in, b_in, w_out, b_out, out);
}

// Round 3
// 733.162 us; speedup vs baseline: 7.1767x; 7.1767x over previous
//
#include <hip/hip_runtime.h>
#include <hip/hip_bf16.h>

typedef __attribute__((ext_vector_type(8))) short short8;
typedef __attribute__((ext_vector_type(4))) float f32x4;

static __device__ __forceinline__ f32x4 MFMA16(short8 a, short8 b, f32x4 c) {
    return __builtin_amdgcn_mfma_f32_16x16x32_bf16(a, b, c, 0, 0, 0);
}

static __device__ __forceinline__ unsigned short f2bf(float f) {
    union { __hip_bfloat16 h; unsigned short u; } c;
    c.h = __float2bfloat16(f);
    return c.u;
}

// ---------------- ws layout ----------------
// wr  : bf16 [12][96][384]   @ 0         (884736 B)  head-reordered w_in
// brr : f32  [1152]          @ 884736    (4608 B)    head-reordered b_in
// wo  : bf16 [384][384]      @ 889344    (294912 B)
// att : bf16 [131072][384]   @ 1184256   (100663296 B)
constexpr size_t kWrOff  = 0;
constexpr size_t kBrOff  = 884736;
constexpr size_t kWoOff  = 889344;
constexpr size_t kAttOff = 1184256;

// ================= kernel 0: prep (convert + reorder weights) =================
__global__ void prep(const float* __restrict__ w_in, const float* __restrict__ b_in,
                     const float* __restrict__ w_out,
                     unsigned short* __restrict__ wr, float* __restrict__ brr,
                     unsigned short* __restrict__ wo)
{
    int i = blockIdx.x * 256 + threadIdx.x;   // grid covers 442368
    {
        int k = i % 384, j = (i / 384) % 96, h = i / (384 * 96);
        int sec = j >> 5, d = j & 31;
        int srow = sec * 384 + h * 32 + d;
        wr[i] = f2bf(w_in[(size_t)srow * 384 + k]);
    }
    if (i < 12 * 96) {
        int j = i % 96, h = i / 96;
        int sec = j >> 5, d = j & 31;
        brr[i] = b_in[sec * 384 + h * 32 + d];
    }
    if (i < 384 * 384) wo[i] = f2bf(w_out[i]);
}

// ================= kernel A: QKV projection + window attention =================
// grid: 1024 m-blocks x 12 heads = 12288. block = 256 thr (4 waves).
// BM=128 (8 windows), BN=96 (q32|k32|v32 of one head), BK=64.
__global__ __launch_bounds__(256, 2)
void qkv_attn(const float* __restrict__ x, const unsigned short* __restrict__ wr,
              const float* __restrict__ brr, unsigned short* __restrict__ att)
{
    // LDS: A-stage 2x[128][144B] = 36864 ; B-stage 2x[96][144B] = 27648 -> 64512
    // attn (aliases A region): qk [128][144B]=18432 ; vT [32][272B]=8704 @18432 ; PT 4x1280 @27136
    __shared__ __align__(16) char smem[64512];

    const int tid  = threadIdx.x;
    const int lane = tid & 63, wid = tid >> 6;
    const int g = lane >> 4, r16 = lane & 15;
    const int wm = wid >> 1, wn = wid & 1;

    // XCD-chunked swizzle: 12288 % 8 == 0
    int b = blockIdx.x;
    int L = (b & 7) * 1536 + (b >> 3);
    const int mblk = L / 12, head = L - mblk * 12;

    // ---- staging maps ----
    const int arow = tid >> 1, ahalf = tid & 1;
    int T0 = mblk * 128 + arow;
    int win0 = T0 >> 4, t4 = T0 & 15;
    int bb0 = win0 >> 8, wh = (win0 >> 4) & 15, ww = win0 & 15;
    const float* xrow = x + ((size_t)bb0 * 4096 +
                             (size_t)((wh * 4 + (t4 >> 2)) * 64 + ww * 4 + (t4 & 3))) * 384
                          + ahalf * 32;
    const unsigned short* brow = wr + ((size_t)head * 96 + (tid >> 1)) * 384 + ahalf * 32;
    char* a_w = smem + (arow * 144 + ahalf * 64);
    char* b_w = smem + 36864 + ((tid >> 1) * 144 + ahalf * 64);

    float4 af[8];
    uint4  bfr[4];

    auto load_step = [&](int s) {
        const float4* xp = (const float4*)(xrow + s * 64);
        #pragma unroll
        for (int j = 0; j < 8; ++j) af[j] = xp[j];
        if (tid < 192) {
            const uint4* bp = (const uint4*)(brow + s * 64);
            #pragma unroll
            for (int j = 0; j < 4; ++j) bfr[j] = bp[j];
        }
    };
    auto write_step = [&](int buf) {
        char* aw = a_w + buf * 18432;
        #pragma unroll
        for (int j = 0; j < 4; ++j) {
            uint4 w;
            w.x = f2bf(af[2*j].x)   | ((unsigned)f2bf(af[2*j].y)   << 16);
            w.y = f2bf(af[2*j].z)   | ((unsigned)f2bf(af[2*j].w)   << 16);
            w.z = f2bf(af[2*j+1].x) | ((unsigned)f2bf(af[2*j+1].y) << 16);
            w.w = f2bf(af[2*j+1].z) | ((unsigned)f2bf(af[2*j+1].w) << 16);
            *(uint4*)(aw + j * 16) = w;
        }
        if (tid < 192) {
            char* bw = b_w + buf * 13824;
            #pragma unroll
            for (int j = 0; j < 4; ++j) *(uint4*)(bw + j * 16) = bfr[j];
        }
    };

    f32x4 acc[4][3] = {};
    auto compute = [&](int buf) {
        const char* ab = smem + buf * 18432;
        const char* bb = smem + 36864 + buf * 13824;
        #pragma unroll
        for (int c = 0; c < 2; ++c) {
            short8 a[4], bf[3];
            #pragma unroll
            for (int mi = 0; mi < 4; ++mi)
                a[mi] = *(const short8*)(ab + (wm * 64 + mi * 16 + r16) * 144 + c * 64 + g * 16);
            #pragma unroll
            for (int ni = 0; ni < 3; ++ni)
                bf[ni] = *(const short8*)(bb + (wn * 48 + ni * 16 + r16) * 144 + c * 64 + g * 16);
            #pragma unroll
            for (int mi = 0; mi < 4; ++mi)
                #pragma unroll
                for (int ni = 0; ni < 3; ++ni)
                    acc[mi][ni] = MFMA16(a[mi], bf[ni], acc[mi][ni]);
        }
    };

    load_step(0);
    write_step(0);
    for (int s = 0; s < 6; ++s) {
        if (s < 5) load_step(s + 1);
        __syncthreads();
        compute(s & 1);
        __syncthreads();
        if (s < 5) write_step((s + 1) & 1);
    }
    // after final compute+sync, staging LDS is dead -> alias for attention

    // ---- epilogue: accums (+bias) -> qk_lds / vT ----
    float bias[3];
    #pragma unroll
    for (int ni = 0; ni < 3; ++ni) bias[ni] = brr[head * 96 + wn * 48 + ni * 16 + r16];

    #pragma unroll
    for (int mi = 0; mi < 4; ++mi) {
        #pragma unroll
        for (int ni = 0; ni < 3; ++ni) {
            const int cb = wn * 48 + ni * 16;   // block col base (wave-uniform)
            if (cb < 64) {
                #pragma unroll
                for (int r = 0; r < 4; ++r) {
                    int tok = wm * 64 + mi * 16 + g * 4 + r;
                    *(unsigned short*)(smem + tok * 144 + (cb + r16) * 2) =
                        f2bf(acc[mi][ni][r] + bias[ni]);
                }
            } else {
                int d = cb - 64 + r16;
                unsigned p0 = f2bf(acc[mi][ni][0] + bias[ni]) |
                              ((unsigned)f2bf(acc[mi][ni][1] + bias[ni]) << 16);
                unsigned p1 = f2bf(acc[mi][ni][2] + bias[ni]) |
                              ((unsigned)f2bf(acc[mi][ni][3] + bias[ni]) << 16);
                int tok0 = wm * 64 + mi * 16 + g * 4;
                *(uint2*)(smem + 18432 + d * 272 + tok0 * 2) = make_uint2(p0, p1);
            }
        }
    }
    // zero the K-pad region of this wave's PT tile (keys 16..31 read as 0)
    char* pt = smem + 27136 + wid * 1280;
    {
        int row = lane >> 2, j = lane & 3;
        *(uint2*)(pt + row * 80 + 32 + j * 8) = make_uint2(0, 0);
    }
    __syncthreads();

    // ---- attention: each wave does 2 windows ----
    const float kC = 0.17677669529663687f * 1.4426950408889634f;  // (1/sqrt(32))*log2(e)
    const f32x4 zero = {0.f, 0.f, 0.f, 0.f};
    #pragma unroll
    for (int i = 0; i < 2; ++i) {
        __syncthreads();               // WAR guard on PT between iterations
        const int win = wid * 2 + i;
        const char* qb = smem + (win * 16 + r16) * 144;
        short8 kf = *(const short8*)(qb + 64 + g * 16);   // A: K  [key=r16][d=g*8+i]
        short8 qf = *(const short8*)(qb + g * 16);        // B: Q  [q=r16][d=g*8+i]
        f32x4 s = MFMA16(kf, qf, zero);                   // D[key=4g+r][q=r16]

        float m = fmaxf(fmaxf(s[0], s[1]), fmaxf(s[2], s[3]));
        m = fmaxf(m, __shfl_xor(m, 16, 64));
        m = fmaxf(m, __shfl_xor(m, 32, 64));
        float p[4], sum = 0.f;
        #pragma unroll
        for (int r = 0; r < 4; ++r) { p[r] = exp2f((s[r] - m) * kC); sum += p[r]; }
        sum += __shfl_xor(sum, 16, 64);
        sum += __shfl_xor(sum, 32, 64);
        const float inv = 1.f / sum;

        // P^T -> PT[q=r16][keys 4g..4g+3]
        unsigned w0 = f2bf(p[0] * inv) | ((unsigned)f2bf(p[1] * inv) << 16);
        unsigned w1 = f2bf(p[2] * inv) | ((unsigned)f2bf(p[3] * inv) << 16);
        *(uint2*)(pt + r16 * 80 + g * 8) = make_uint2(w0, w1);
        __syncthreads();               // PT visible/ordered before fragment read

        short8 pa = *(const short8*)(pt + r16 * 80 + g * 16);  // A: P^T[q=r16][k=g*8+i]
        f32x4 o[2];
        #pragma unroll
        for (int ti = 0; ti < 2; ++ti) {
            short8 vb = (short8)0;
            if (g < 2)  // keys g*8..g*8+7 real; keys>=16 zero
                vb = *(const short8*)(smem + 18432 + (r16 + ti * 16) * 272 + win * 32 + g * 16);
            o[ti] = MFMA16(pa, vb, zero);                 // D[q=4g+r][d=r16]
        }
        size_t Tb = ((size_t)mblk * 128 + win * 16) * 384 + head * 32;
        #pragma unroll
        for (int ti = 0; ti < 2; ++ti)
            #pragma unroll
            for (int r = 0; r < 4; ++r)
                att[Tb + (size_t)(g * 4 + r) * 384 + ti * 16 + r16] = f2bf(o[ti][r]);
    }
}

// ================= kernel B: out projection =================
// grid: 1024 m-blocks x 3 n-blocks = 3072. BM=128, BN=128, BK=64, single-buffered.
__global__ __launch_bounds__(256, 2)
void out_proj(const unsigned short* __restrict__ att, const unsigned short* __restrict__ wo,
              const float* __restrict__ b_out, float* __restrict__ out)
{
    __shared__ __align__(16) char smem[36864];  // A [128][144B] @0 ; B [128][144B] @18432

    const int tid  = threadIdx.x;
    const int lane = tid & 63, wid = tid >> 6;
    const int g = lane >> 4, r16 = lane & 15;
    const int wm = wid >> 1, wn = wid & 1;

    int b = blockIdx.x;
    int L = (b & 7) * 384 + (b >> 3);
    const int mblk = L / 3, nblk = L - mblk * 3;

    const int row2 = tid >> 1, half = tid & 1;
    const unsigned short* arow = att + ((size_t)mblk * 128 + row2) * 384 + half * 32;
    const unsigned short* brow = wo + ((size_t)nblk * 128 + row2) * 384 + half * 32;
    char* aw = smem + row2 * 144 + half * 64;
    char* bw = smem + 18432 + row2 * 144 + half * 64;

    uint4 afr[4], bfr[4];
    auto load_step = [&](int s) {
        const uint4* ap = (const uint4*)(arow + s * 64);
        const uint4* bp = (const uint4*)(brow + s * 64);
        #pragma unroll
        for (int j = 0; j < 4; ++j) { afr[j] = ap[j]; bfr[j] = bp[j]; }
    };
    auto write_step = [&]() {
        #pragma unroll
        for (int j = 0; j < 4; ++j) {
            *(uint4*)(aw + j * 16) = afr[j];
            *(uint4*)(bw + j * 16) = bfr[j];
        }
    };

    f32x4 acc[4][4] = {};
    auto compute = [&]() {
        #pragma unroll
        for (int c = 0; c < 2; ++c) {
            short8 a[4], bf[4];
            #pragma unroll
            for (int mi = 0; mi < 4; ++mi)
                a[mi] = *(const short8*)(smem + (wm * 64 + mi * 16 + r16) * 144 + c * 64 + g * 16);
            #pragma unroll
            for (int ni = 0; ni < 4; ++ni)
                bf[ni] = *(const short8*)(smem + 18432 + (wn * 64 + ni * 16 + r16) * 144 + c * 64 + g * 16);
            #pragma unroll
            for (int mi = 0; mi < 4; ++mi)
                #pragma unroll
                for (int ni = 0; ni < 4; ++ni)
                    acc[mi][ni] = MFMA16(a[mi], bf[ni], acc[mi][ni]);
        }
    };

    load_step(0);
    write_step();
    for (int s = 0; s < 6; ++s) {
        if (s < 5) load_step(s + 1);   // issue next loads early (hide under compute)
        __syncthreads();
        compute();
        __syncthreads();
        if (s < 5) write_step();
    }

    float bias[4];
    #pragma unroll
    for (int ni = 0; ni < 4; ++ni) bias[ni] = b_out[nblk * 128 + wn * 64 + ni * 16 + r16];

    #pragma unroll
    for (int mi = 0; mi < 4; ++mi) {
        #pragma unroll
        for (int r = 0; r < 4; ++r) {
            int T = mblk * 128 + wm * 64 + mi * 16 + g * 4 + r;
            int win = T >> 4, tt = T & 15;
            int bb = win >> 8, wh = (win >> 4) & 15, ww = win & 15;
            size_t o = ((size_t)bb * 4096 + (wh * 4 + (tt >> 2)) * 64 + ww * 4 + (tt & 3)) * 384
                     + nblk * 128 + wn * 64;
            #pragma unroll
            for (int ni = 0; ni < 4; ++ni)
                out[o + ni * 16 + r16] = acc[mi][ni][r] + bias[ni];
        }
    }
}

extern "C" void kernel_launch(void* const* d_in, const int* in_sizes, int n_in,
                              void* d_out, int out_size, void* d_ws, size_t ws_size,
                              hipStream_t stream) {
    const float* x     = (const float*)d_in[0];
    const float* w_in  = (const float*)d_in[1];
    const float* b_in  = (const float*)d_in[2];
    const float* w_out = (const float*)d_in[3];
    const float* b_out = (const float*)d_in[4];
    float* out = (float*)d_out;

    char* ws = (char*)d_ws;
    unsigned short* wr  = (unsigned short*)(ws + kWrOff);
    float*          brr = (float*)(ws + kBrOff);
    unsigned short* wo  = (unsigned short*)(ws + kWoOff);
    unsigned short* att = (unsigned short*)(ws + kAttOff);

    prep<<<dim3(1728), dim3(256), 0, stream>>>(w_in, b_in, w_out, wr, brr, wo);
    qkv_attn<<<dim3(12288), dim3(256), 0, stream>>>(x, wr, brr, att);
    out_proj<<<dim3(3072), dim3(256), 0, stream>>>(att, wo, b_out, out);
}

// Round 4
// 335.949 us; speedup vs baseline: 15.6621x; 2.1824x over previous
//
#include <hip/hip_runtime.h>
#include <hip/hip_bf16.h>

typedef __attribute__((ext_vector_type(8))) short short8;
typedef __attribute__((ext_vector_type(4))) float f32x4;

static __device__ __forceinline__ f32x4 MFMA16(short8 a, short8 b, f32x4 c) {
    return __builtin_amdgcn_mfma_f32_16x16x32_bf16(a, b, c, 0, 0, 0);
}
static __device__ __forceinline__ unsigned short f2bf(float f) {
    union { __hip_bfloat16 h; unsigned short u; } c;
    c.h = __float2bfloat16(f);
    return c.u;
}
static __device__ __forceinline__ void gload16(const void* g, void* l) {
    __builtin_amdgcn_global_load_lds(
        (const __attribute__((address_space(1))) unsigned int*)g,
        (__attribute__((address_space(3))) unsigned int*)l, 16, 0, 0);
}

// ---------------- ws layout ----------------
// wst  : bf16, LDS-order pre-swizzled w_in  [6 hp][6 s][1536 granules x16B] @ 0        (884736)
// wos  : bf16, LDS-order pre-swizzled w_out [3 nb][6 s][1024 granules x16B] @ 884736   (294912)
// brr  : f32  [12][96] head-major bias                                      @ 1179648  (4608)
// attst: bf16, LDS-order pre-swizzled att   [1024 mb][6 s][16384 B]         @ 1184256  (100663296)
constexpr size_t kWstOff = 0;
constexpr size_t kWosOff = 884736;
constexpr size_t kBrrOff = 1179648;
constexpr size_t kAttOff = 1184256;

// ================= kernel 0: prep (convert + reorder + pre-swizzle weights) =====
__global__ void prep(const float* __restrict__ w_in, const float* __restrict__ b_in,
                     const float* __restrict__ w_out,
                     char* __restrict__ wst, char* __restrict__ wos,
                     float* __restrict__ brr)
{
    const int i = blockIdx.x * 256 + threadIdx.x;   // grid covers 73728 exactly
    if (i < 55296) {
        // wst granule i: hp, step s, slot16 -> row(192), slot; col8 = slot ^ (row&7)
        int hp = i / 9216, rem = i % 9216;
        int s = rem / 1536, slot16 = rem % 1536;
        int row = slot16 >> 3, sl = slot16 & 7;
        int c8 = sl ^ (row & 7);
        int hh = row / 96, rr = row % 96;
        int sec = rr >> 5, d = rr & 31;
        int srow = sec * 384 + (hp * 2 + hh) * 32 + d;
        int k0 = s * 64 + c8 * 8;
        const float4* src = (const float4*)(w_in + (size_t)srow * 384 + k0);
        float4 a = src[0], b = src[1];
        uint4 w;
        w.x = f2bf(a.x) | ((unsigned)f2bf(a.y) << 16);
        w.y = f2bf(a.z) | ((unsigned)f2bf(a.w) << 16);
        w.z = f2bf(b.x) | ((unsigned)f2bf(b.y) << 16);
        w.w = f2bf(b.z) | ((unsigned)f2bf(b.w) << 16);
        *(uint4*)(wst + (size_t)i * 16) = w;
    } else {
        // wos granule
        int j = i - 55296;                           // [0, 18432)
        int nb = j / 6144, rem = j % 6144;
        int s = rem / 1024, slot16 = rem % 1024;
        int row = slot16 >> 3, sl = slot16 & 7;
        int c8 = sl ^ (row & 7);
        int srow = nb * 128 + row;
        int k0 = s * 64 + c8 * 8;
        const float4* src = (const float4*)(w_out + (size_t)srow * 384 + k0);
        float4 a = src[0], b = src[1];
        uint4 w;
        w.x = f2bf(a.x) | ((unsigned)f2bf(a.y) << 16);
        w.y = f2bf(a.z) | ((unsigned)f2bf(a.w) << 16);
        w.z = f2bf(b.x) | ((unsigned)f2bf(b.y) << 16);
        w.w = f2bf(b.z) | ((unsigned)f2bf(b.w) << 16);
        *(uint4*)(wos + (size_t)j * 16) = w;
    }
    if (i < 1152) {
        int h = i / 96, jj = i % 96;
        int sec = jj >> 5, d = jj & 31;
        brr[i] = b_in[sec * 384 + h * 32 + d];
    }
}

// ================= kernel A: QKV projection + window attention =================
// grid: 1024 m-blocks x 6 head-pairs = 6144. block = 256 thr (4 waves).
// BM=128 (8 windows), BN=192 (2 heads x q32|k32|v32), BK=64.
// LDS 64KB: A [128][128B] @0 (single-buf) ; B 2x[192][128B] @16384
// attn alias: QKV^T tiles [8 win][2 head][3 sec][32 d][16 t] @0 (48KB); PT @49152+wid*1280
__global__ __launch_bounds__(256, 2)
void qkv_attn(const float* __restrict__ x, const char* __restrict__ wst,
              const float* __restrict__ brr, char* __restrict__ attst)
{
    __shared__ __align__(16) char smem[65536];

    const int tid  = threadIdx.x;
    const int lane = tid & 63, wid = tid >> 6;
    const int g = lane >> 4, r16 = lane & 15;
    const int wm = wid >> 1, wn = wid & 1;

    int b = blockIdx.x;
    int L = (b & 7) * 768 + (b >> 3);          // XCD-chunked swizzle (6144 % 8 == 0)
    const int mblk = L / 6, hp = L - mblk * 6;
    const int head = hp * 2 + wn;

    // ---- A staging map (x, f32 -> bf16, swizzled writes) ----
    const int arow = tid >> 1, ahalf = tid & 1;
    int T0 = mblk * 128 + arow;
    int win0 = T0 >> 4, t4 = T0 & 15;
    int bb0 = win0 >> 8, wh = (win0 >> 4) & 15, ww = win0 & 15;
    const float* xrow = x + ((size_t)bb0 * 4096 +
                             (size_t)((wh * 4 + (t4 >> 2)) * 64 + ww * 4 + (t4 & 3))) * 384
                          + ahalf * 32;

    float4 af[8];
    auto load_A = [&](int s) {
        const float4* xp = (const float4*)(xrow + s * 64);
        #pragma unroll
        for (int j = 0; j < 8; ++j) af[j] = xp[j];
    };
    auto write_A = [&]() {
        #pragma unroll
        for (int j = 0; j < 4; ++j) {
            uint4 w;
            w.x = f2bf(af[2*j].x)   | ((unsigned)f2bf(af[2*j].y)   << 16);
            w.y = f2bf(af[2*j].z)   | ((unsigned)f2bf(af[2*j].w)   << 16);
            w.z = f2bf(af[2*j+1].x) | ((unsigned)f2bf(af[2*j+1].y) << 16);
            w.w = f2bf(af[2*j+1].z) | ((unsigned)f2bf(af[2*j+1].w) << 16);
            int slot = (ahalf * 4 + j) ^ (arow & 7);
            *(uint4*)(smem + arow * 128 + slot * 16) = w;
        }
    };
    const char* wst_blk = wst + (size_t)hp * 147456;
    auto stage_B = [&](int s, int buf) {
        char* dst = smem + 16384 + buf * 24576 + wid * 6144;
        const char* src = wst_blk + s * 24576 + wid * 6144 + lane * 16;
        #pragma unroll
        for (int j = 0; j < 6; ++j) gload16(src + j * 1024, dst + j * 1024);
    };

    f32x4 acc[4][6] = {};
    auto compute = [&](int buf) {
        const char* bbp = smem + 16384 + buf * 24576;
        #pragma unroll
        for (int c = 0; c < 2; ++c) {
            const int sw = ((c * 4 + g) ^ (r16 & 7)) << 4;
            short8 a[4], bf[6];
            #pragma unroll
            for (int mi = 0; mi < 4; ++mi)
                a[mi] = *(const short8*)(smem + (wm * 64 + mi * 16 + r16) * 128 + sw);
            #pragma unroll
            for (int ni = 0; ni < 6; ++ni)
                bf[ni] = *(const short8*)(bbp + (wn * 96 + ni * 16 + r16) * 128 + sw);
            #pragma unroll
            for (int mi = 0; mi < 4; ++mi)
                #pragma unroll
                for (int ni = 0; ni < 6; ++ni)
                    acc[mi][ni] = MFMA16(a[mi], bf[ni], acc[mi][ni]);
        }
    };

    // prologue
    load_A(0);
    stage_B(0, 0);
    write_A();
    // main loop: 2 barriers/step; B gloads double-buffered, A reg-staged single-buf
    for (int s = 0; s < 6; ++s) {
        __syncthreads();                        // B(s) + A visible
        if (s < 5) { stage_B(s + 1, (s + 1) & 1); load_A(s + 1); }
        compute(s & 1);
        __syncthreads();                        // all waves done reading A
        if (s < 5) write_A();
    }
    // loop ends after sync2 of s=5 -> staging LDS dead; epilogue+attention are
    // fully wave-local (each wave wrote its own windows' tiles): NO barriers.

    // ---- epilogue: acc (+bias) -> Q^T/K^T/V^T tiles [d][t], one b64 per tile ----
    float bias[6];
    #pragma unroll
    for (int ni = 0; ni < 6; ++ni) bias[ni] = brr[head * 96 + ni * 16 + r16];

    #pragma unroll
    for (int mi = 0; mi < 4; ++mi) {
        const int win = wm * 4 + mi;
        #pragma unroll
        for (int ni = 0; ni < 6; ++ni) {
            const int sec = ni >> 1;            // 0=Q 1=K 2=V
            const int d = (ni & 1) * 16 + r16;
            float v0 = acc[mi][ni][0] + bias[ni];
            float v1 = acc[mi][ni][1] + bias[ni];
            float v2 = acc[mi][ni][2] + bias[ni];
            float v3 = acc[mi][ni][3] + bias[ni];
            uint2 w;
            w.x = f2bf(v0) | ((unsigned)f2bf(v1) << 16);
            w.y = f2bf(v2) | ((unsigned)f2bf(v3) << 16);
            *(uint2*)(smem + win * 6144 + wn * 3072 + sec * 1024 + d * 32 + g * 8) = w;
        }
    }

    // ---- attention: 4 windows per wave, zero barriers ----
    const float kC = 0.17677669529663687f * 1.4426950408889634f;  // (1/sqrt32)*log2e
    const f32x4 zero = {0.f, 0.f, 0.f, 0.f};
    char* pt = smem + 49152 + wid * 1280;       // [16 q][80B] (upper 48B garbage-finite)

    #pragma unroll
    for (int i = 0; i < 4; ++i) {
        const int win = wm * 4 + i;
        const char* base = smem + win * 6144 + wn * 3072;

        union U8 { unsigned short e[8]; short8 v; };
        U8 ku, qu;
        #pragma unroll
        for (int j = 0; j < 8; ++j) {
            const int off = (g * 8 + j) * 32 + r16 * 2;   // elem (d, t=r16)
            qu.e[j] = *(const unsigned short*)(base + off);
            ku.e[j] = *(const unsigned short*)(base + 1024 + off);
        }
        f32x4 s = MFMA16(ku.v, qu.v, zero);     // D[key=4g+r][q=r16]

        float m = fmaxf(fmaxf(s[0], s[1]), fmaxf(s[2], s[3]));
        m = fmaxf(m, __shfl_xor(m, 16, 64));
        m = fmaxf(m, __shfl_xor(m, 32, 64));
        float p[4], sum = 0.f;
        #pragma unroll
        for (int r = 0; r < 4; ++r) { p[r] = exp2f((s[r] - m) * kC); sum += p[r]; }
        sum += __shfl_xor(sum, 16, 64);
        sum += __shfl_xor(sum, 32, 64);
        const float inv = 1.f / sum;

        uint2 pw;
        pw.x = f2bf(p[0] * inv) | ((unsigned)f2bf(p[1] * inv) << 16);
        pw.y = f2bf(p[2] * inv) | ((unsigned)f2bf(p[3] * inv) << 16);
        *(uint2*)(pt + r16 * 80 + g * 8) = pw;  // PT[q=r16][keys 4g..4g+3]

        short8 pa = *(const short8*)(pt + r16 * 80 + g * 16);  // P^T[q=r16][k=g*8+j]
        f32x4 o[2];
        #pragma unroll
        for (int ti = 0; ti < 2; ++ti) {
            short8 vb = (short8)0;              // keys >=16 contribute zero via B=0
            if (g < 2)
                vb = *(const short8*)(base + 2048 + (ti * 16 + r16) * 32 + g * 16);
            o[ti] = MFMA16(pa, vb, zero);       // D[q=4g+r][d-col=r16]
        }
        // store att pre-swizzled for out_proj's global_load_lds staging
        #pragma unroll
        for (int ti = 0; ti < 2; ++ti) {
            #pragma unroll
            for (int r = 0; r < 4; ++r) {
                int row7 = win * 16 + g * 4 + r;
                int col = head * 32 + ti * 16 + r16;
                int sst = col >> 6;
                int sl = ((col >> 3) & 7) ^ (row7 & 7);
                *(unsigned short*)(attst + (size_t)mblk * 98304 + sst * 16384
                                   + row7 * 128 + sl * 16 + (col & 7) * 2)
                    = f2bf(o[ti][r]);
            }
        }
    }
}

// ================= kernel B: out projection =================
// grid: 1024 m-blocks x 3 n-blocks = 3072. BM=128, BN=128, BK=64.
// Both operands staged via global_load_lds (pre-swizzled sources), 1 barrier/step.
__global__ __launch_bounds__(256, 2)
void out_proj(const char* __restrict__ attst, const char* __restrict__ wos,
              const float* __restrict__ b_out, float* __restrict__ out)
{
    __shared__ __align__(16) char smem[65536];  // A 2x16K @0 ; B 2x16K @32768

    const int tid  = threadIdx.x;
    const int lane = tid & 63, wid = tid >> 6;
    const int g = lane >> 4, r16 = lane & 15;
    const int wm = wid >> 1, wn = wid & 1;

    int b = blockIdx.x;
    int L = (b & 7) * 384 + (b >> 3);
    const int mblk = L / 3, nblk = L - mblk * 3;

    auto stage = [&](int s, int buf) {
        const char* asrc = attst + (size_t)mblk * 98304 + s * 16384 + wid * 4096 + lane * 16;
        const char* bsrc = wos   + (size_t)nblk * 98304 + s * 16384 + wid * 4096 + lane * 16;
        char* adst = smem + buf * 16384 + wid * 4096;
        char* bdst = smem + 32768 + buf * 16384 + wid * 4096;
        #pragma unroll
        for (int j = 0; j < 4; ++j) {
            gload16(asrc + j * 1024, adst + j * 1024);
            gload16(bsrc + j * 1024, bdst + j * 1024);
        }
    };

    f32x4 acc[4][4] = {};
    auto compute = [&](int buf) {
        const char* ab = smem + buf * 16384;
        const char* bbp = smem + 32768 + buf * 16384;
        #pragma unroll
        for (int c = 0; c < 2; ++c) {
            const int sw = ((c * 4 + g) ^ (r16 & 7)) << 4;
            short8 a[4], bf[4];
            #pragma unroll
            for (int mi = 0; mi < 4; ++mi)
                a[mi] = *(const short8*)(ab + (wm * 64 + mi * 16 + r16) * 128 + sw);
            #pragma unroll
            for (int ni = 0; ni < 4; ++ni)
                bf[ni] = *(const short8*)(bbp + (wn * 64 + ni * 16 + r16) * 128 + sw);
            #pragma unroll
            for (int mi = 0; mi < 4; ++mi)
                #pragma unroll
                for (int ni = 0; ni < 4; ++ni)
                    acc[mi][ni] = MFMA16(a[mi], bf[ni], acc[mi][ni]);
        }
    };

    stage(0, 0);
    for (int s = 0; s < 6; ++s) {
        __syncthreads();                 // stage(s) landed; all waves past compute(s-1)
        if (s < 5) stage(s + 1, (s + 1) & 1);
        compute(s & 1);
    }

    float bias[4];
    #pragma unroll
    for (int ni = 0; ni < 4; ++ni) bias[ni] = b_out[nblk * 128 + wn * 64 + ni * 16 + r16];

    #pragma unroll
    for (int mi = 0; mi < 4; ++mi) {
        #pragma unroll
        for (int r = 0; r < 4; ++r) {
            int T = mblk * 128 + wm * 64 + mi * 16 + g * 4 + r;
            int win = T >> 4, tt = T & 15;
            int bb = win >> 8, wh = (win >> 4) & 15, ww = win & 15;
            size_t o = ((size_t)bb * 4096 + (wh * 4 + (tt >> 2)) * 64 + ww * 4 + (tt & 3)) * 384
                     + nblk * 128 + wn * 64;
            #pragma unroll
            for (int ni = 0; ni < 4; ++ni)
                out[o + ni * 16 + r16] = acc[mi][ni][r] + bias[ni];
        }
    }
}

extern "C" void kernel_launch(void* const* d_in, const int* in_sizes, int n_in,
                              void* d_out, int out_size, void* d_ws, size_t ws_size,
                              hipStream_t stream) {
    const float* x     = (const float*)d_in[0];
    const float* w_in  = (const float*)d_in[1];
    const float* b_in  = (const float*)d_in[2];
    const float* w_out = (const float*)d_in[3];
    const float* b_out = (const float*)d_in[4];
    float* out = (float*)d_out;

    char* ws = (char*)d_ws;
    char*  wst = ws + kWstOff;
    char*  wos = ws + kWosOff;
    float* brr = (float*)(ws + kBrrOff);
    char*  att = ws + kAttOff;

    prep<<<dim3(288), dim3(256), 0, stream>>>(w_in, b_in, w_out, wst, wos, brr);
    qkv_attn<<<dim3(6144), dim3(256), 0, stream>>>(x, wst, brr, att);
    out_proj<<<dim3(3072), dim3(256), 0, stream>>>(att, wos, b_out, out);
}

// Round 5
// 333.806 us; speedup vs baseline: 15.7626x; 1.0064x over previous
//
#include <hip/hip_runtime.h>
#include <hip/hip_bf16.h>

typedef __attribute__((ext_vector_type(8))) short short8;
typedef __attribute__((ext_vector_type(4))) float f32x4;

static __device__ __forceinline__ f32x4 MFMA16(short8 a, short8 b, f32x4 c) {
    return __builtin_amdgcn_mfma_f32_16x16x32_bf16(a, b, c, 0, 0, 0);
}
static __device__ __forceinline__ unsigned short f2bf(float f) {
    union { __hip_bfloat16 h; unsigned short u; } c;
    c.h = __float2bfloat16(f);
    return c.u;
}
static __device__ __forceinline__ void gload16(const void* g, void* l) {
    __builtin_amdgcn_global_load_lds(
        (const __attribute__((address_space(1))) unsigned int*)g,
        (__attribute__((address_space(3))) unsigned int*)l, 16, 0, 0);
}

// ---------------- ws layout ----------------
// wst  : bf16, LDS-order pre-swizzled w_in  [6 hp][6 s][1536 granules x16B] @ 0        (884736)
// wos  : bf16, LDS-order pre-swizzled w_out [3 nb][6 s][1024 granules x16B] @ 884736   (294912)
// brr  : f32  [12][96] head-major bias                                      @ 1179648  (4608)
// attst: bf16, LDS-order pre-swizzled att   [1024 mb][6 s][16384 B]         @ 1184256  (100663296)
constexpr size_t kWstOff = 0;
constexpr size_t kWosOff = 884736;
constexpr size_t kBrrOff = 1179648;
constexpr size_t kAttOff = 1184256;

// ================= kernel 0: prep (convert + reorder + pre-swizzle weights) =====
__global__ void prep(const float* __restrict__ w_in, const float* __restrict__ b_in,
                     const float* __restrict__ w_out,
                     char* __restrict__ wst, char* __restrict__ wos,
                     float* __restrict__ brr)
{
    const int i = blockIdx.x * 256 + threadIdx.x;   // grid covers 73728 exactly
    if (i < 55296) {
        int hp = i / 9216, rem = i % 9216;
        int s = rem / 1536, slot16 = rem % 1536;
        int row = slot16 >> 3, sl = slot16 & 7;
        int c8 = sl ^ (row & 7);
        int hh = row / 96, rr = row % 96;
        int sec = rr >> 5, d = rr & 31;
        int srow = sec * 384 + (hp * 2 + hh) * 32 + d;
        int k0 = s * 64 + c8 * 8;
        const float4* src = (const float4*)(w_in + (size_t)srow * 384 + k0);
        float4 a = src[0], b = src[1];
        uint4 w;
        w.x = f2bf(a.x) | ((unsigned)f2bf(a.y) << 16);
        w.y = f2bf(a.z) | ((unsigned)f2bf(a.w) << 16);
        w.z = f2bf(b.x) | ((unsigned)f2bf(b.y) << 16);
        w.w = f2bf(b.z) | ((unsigned)f2bf(b.w) << 16);
        *(uint4*)(wst + (size_t)i * 16) = w;
    } else {
        int j = i - 55296;                           // [0, 18432)
        int nb = j / 6144, rem = j % 6144;
        int s = rem / 1024, slot16 = rem % 1024;
        int row = slot16 >> 3, sl = slot16 & 7;
        int c8 = sl ^ (row & 7);
        int srow = nb * 128 + row;
        int k0 = s * 64 + c8 * 8;
        const float4* src = (const float4*)(w_out + (size_t)srow * 384 + k0);
        float4 a = src[0], b = src[1];
        uint4 w;
        w.x = f2bf(a.x) | ((unsigned)f2bf(a.y) << 16);
        w.y = f2bf(a.z) | ((unsigned)f2bf(a.w) << 16);
        w.z = f2bf(b.x) | ((unsigned)f2bf(b.y) << 16);
        w.w = f2bf(b.z) | ((unsigned)f2bf(b.w) << 16);
        *(uint4*)(wos + (size_t)j * 16) = w;
    }
    if (i < 1152) {
        int h = i / 96, jj = i % 96;
        int sec = jj >> 5, d = jj & 31;
        brr[i] = b_in[sec * 384 + h * 32 + d];
    }
}

// ================= kernel A: QKV projection + window attention =================
// grid: 1024 m-blocks x 6 head-pairs = 6144. block = 256 thr (4 waves).
// BM=128 (8 windows), BN=192 (2 heads x q32|k32|v32), BK=64.
// LDS 80KB: A 2x[128][128B] @0 ; B 2x[192][128B] @32768 -> 2 blocks/CU (160KB exact)
// attn alias: QKV^T tiles [8 win][2 head][3 sec][32 d][16 t] @0 (48KB)
__global__ __launch_bounds__(256, 2)
void qkv_attn(const float* __restrict__ x, const char* __restrict__ wst,
              const float* __restrict__ brr, char* __restrict__ attst)
{
    __shared__ __align__(16) char smem[81920];

    const int tid  = threadIdx.x;
    const int lane = tid & 63, wid = tid >> 6;
    const int g = lane >> 4, r16 = lane & 15;
    const int wm = wid >> 1, wn = wid & 1;

    int b = blockIdx.x;
    int L = (b & 7) * 768 + (b >> 3);          // XCD-chunked swizzle (6144 % 8 == 0)
    const int mblk = L / 6, hp = L - mblk * 6;
    const int head = hp * 2 + wn;

    // ---- A staging map (x, f32 -> bf16, swizzled writes, double-buffered) ----
    const int arow = tid >> 1, ahalf = tid & 1;
    int T0 = mblk * 128 + arow;
    int win0 = T0 >> 4, t4 = T0 & 15;
    int bb0 = win0 >> 8, wh = (win0 >> 4) & 15, ww = win0 & 15;
    const float* xrow = x + ((size_t)bb0 * 4096 +
                             (size_t)((wh * 4 + (t4 >> 2)) * 64 + ww * 4 + (t4 & 3))) * 384
                          + ahalf * 32;

    float4 af[8];
    auto load_A = [&](int s) {
        const float4* xp = (const float4*)(xrow + s * 64);
        #pragma unroll
        for (int j = 0; j < 8; ++j) af[j] = xp[j];
    };
    auto write_A = [&](int buf) {
        #pragma unroll
        for (int j = 0; j < 4; ++j) {
            uint4 w;
            w.x = f2bf(af[2*j].x)   | ((unsigned)f2bf(af[2*j].y)   << 16);
            w.y = f2bf(af[2*j].z)   | ((unsigned)f2bf(af[2*j].w)   << 16);
            w.z = f2bf(af[2*j+1].x) | ((unsigned)f2bf(af[2*j+1].y) << 16);
            w.w = f2bf(af[2*j+1].z) | ((unsigned)f2bf(af[2*j+1].w) << 16);
            int slot = (ahalf * 4 + j) ^ (arow & 7);
            *(uint4*)(smem + buf * 16384 + arow * 128 + slot * 16) = w;
        }
    };
    const char* wst_blk = wst + (size_t)hp * 147456;
    auto stage_B = [&](int s, int buf) {
        char* dst = smem + 32768 + buf * 24576 + wid * 6144;
        const char* src = wst_blk + s * 24576 + wid * 6144 + lane * 16;
        #pragma unroll
        for (int j = 0; j < 6; ++j) gload16(src + j * 1024, dst + j * 1024);
    };

    f32x4 acc[4][6] = {};
    auto compute = [&](int buf) {
        const char* ab = smem + buf * 16384;
        const char* bbp = smem + 32768 + buf * 24576;
        #pragma unroll
        for (int c = 0; c < 2; ++c) {
            const int sw = ((c * 4 + g) ^ (r16 & 7)) << 4;
            short8 a[4], bf[6];
            #pragma unroll
            for (int mi = 0; mi < 4; ++mi)
                a[mi] = *(const short8*)(ab + (wm * 64 + mi * 16 + r16) * 128 + sw);
            #pragma unroll
            for (int ni = 0; ni < 6; ++ni)
                bf[ni] = *(const short8*)(bbp + (wn * 96 + ni * 16 + r16) * 128 + sw);
            #pragma unroll
            for (int mi = 0; mi < 4; ++mi)
                #pragma unroll
                for (int ni = 0; ni < 6; ++ni)
                    acc[mi][ni] = MFMA16(a[mi], bf[ni], acc[mi][ni]);
        }
    };

    // prologue
    load_A(0);
    stage_B(0, 0);
    write_A(0);
    // main loop: ONE barrier per K-step (A and B both double-buffered)
    for (int s = 0; s < 6; ++s) {
        __syncthreads();                        // stage_B(s) + write_A(s) visible
        if (s < 5) { load_A(s + 1); stage_B(s + 1, (s + 1) & 1); }
        compute(s & 1);
        if (s < 5) write_A((s + 1) & 1);        // alt buffer: safe vs concurrent readers
    }
    __syncthreads();  // tile-alias region overlaps A-buf1/B-buf0: wait all compute done

    // ---- epilogue: acc (+bias) -> Q^T/K^T/V^T tiles [d][t], one b64 per tile ----
    float bias[6];
    #pragma unroll
    for (int ni = 0; ni < 6; ++ni) bias[ni] = brr[head * 96 + ni * 16 + r16];

    #pragma unroll
    for (int mi = 0; mi < 4; ++mi) {
        const int win = wm * 4 + mi;
        #pragma unroll
        for (int ni = 0; ni < 6; ++ni) {
            const int sec = ni >> 1;            // 0=Q 1=K 2=V
            const int d = (ni & 1) * 16 + r16;
            float v0 = acc[mi][ni][0] + bias[ni];
            float v1 = acc[mi][ni][1] + bias[ni];
            float v2 = acc[mi][ni][2] + bias[ni];
            float v3 = acc[mi][ni][3] + bias[ni];
            uint2 w;
            w.x = f2bf(v0) | ((unsigned)f2bf(v1) << 16);
            w.y = f2bf(v2) | ((unsigned)f2bf(v3) << 16);
            *(uint2*)(smem + win * 6144 + wn * 3072 + sec * 1024 + d * 32 + g * 8) = w;
        }
    }

    // ---- attention: 4 windows per wave, zero barriers, P stays in registers ----
    const float kC = 0.17677669529663687f * 1.4426950408889634f;  // (1/sqrt32)*log2e
    const f32x4 zero = {0.f, 0.f, 0.f, 0.f};

    #pragma unroll
    for (int i = 0; i < 4; ++i) {
        const int win = wm * 4 + i;
        const char* base = smem + win * 6144 + wn * 3072;

        union U8 { unsigned short e[8]; short8 v; };
        U8 ku, qu;
        #pragma unroll
        for (int j = 0; j < 8; ++j) {
            const int off = (g * 8 + j) * 32 + r16 * 2;   // elem (d, t=r16)
            qu.e[j] = *(const unsigned short*)(base + off);
            ku.e[j] = *(const unsigned short*)(base + 1024 + off);
        }
        f32x4 s = MFMA16(ku.v, qu.v, zero);     // D[key=4g+r][q=r16]

        float m = fmaxf(fmaxf(s[0], s[1]), fmaxf(s[2], s[3]));
        m = fmaxf(m, __shfl_xor(m, 16, 64));
        m = fmaxf(m, __shfl_xor(m, 32, 64));
        float p[4], sum = 0.f;
        #pragma unroll
        for (int r = 0; r < 4; ++r) { p[r] = exp2f((s[r] - m) * kC); sum += p[r]; }
        sum += __shfl_xor(sum, 16, 64);
        sum += __shfl_xor(sum, 32, 64);
        const float inv = 1.f / sum;

        // P as in-register A-fragment under k-perm k=4g+j (upper 4 elems zero).
        // Legal because V's B-fragment below uses the SAME key permutation.
        U8 pu;
        pu.e[0] = f2bf(p[0] * inv); pu.e[1] = f2bf(p[1] * inv);
        pu.e[2] = f2bf(p[2] * inv); pu.e[3] = f2bf(p[3] * inv);
        pu.e[4] = 0; pu.e[5] = 0; pu.e[6] = 0; pu.e[7] = 0;

        f32x4 o[2];
        #pragma unroll
        for (int ti = 0; ti < 2; ++ti) {
            U8 vu;                               // V[key=4g+j][d=ti*16+r16], j=0..3
            *(uint2*)&vu.e[0] = *(const uint2*)(base + 2048 + (ti * 16 + r16) * 32 + g * 8);
            vu.e[4] = 0; vu.e[5] = 0; vu.e[6] = 0; vu.e[7] = 0;
            o[ti] = MFMA16(pu.v, vu.v, zero);    // D[q=4g+r][d-col=r16]
        }
        // store att pre-swizzled for out_proj's global_load_lds staging
        #pragma unroll
        for (int ti = 0; ti < 2; ++ti) {
            #pragma unroll
            for (int r = 0; r < 4; ++r) {
                int row7 = win * 16 + g * 4 + r;
                int col = head * 32 + ti * 16 + r16;
                int sst = col >> 6;
                int sl = ((col >> 3) & 7) ^ (row7 & 7);
                *(unsigned short*)(attst + (size_t)mblk * 98304 + sst * 16384
                                   + row7 * 128 + sl * 16 + (col & 7) * 2)
                    = f2bf(o[ti][r]);
            }
        }
    }
}

// ================= kernel B: out projection =================
// grid: 1024 m-blocks x 3 n-blocks = 3072. BM=128, BN=128, BK=64.
__global__ __launch_bounds__(256, 2)
void out_proj(const char* __restrict__ attst, const char* __restrict__ wos,
              const float* __restrict__ b_out, float* __restrict__ out)
{
    __shared__ __align__(16) char smem[65536];  // A 2x16K @0 ; B 2x16K @32768

    const int tid  = threadIdx.x;
    const int lane = tid & 63, wid = tid >> 6;
    const int g = lane >> 4, r16 = lane & 15;
    const int wm = wid >> 1, wn = wid & 1;

    int b = blockIdx.x;
    int L = (b & 7) * 384 + (b >> 3);
    const int mblk = L / 3, nblk = L - mblk * 3;

    auto stage = [&](int s, int buf) {
        const char* asrc = attst + (size_t)mblk * 98304 + s * 16384 + wid * 4096 + lane * 16;
        const char* bsrc = wos   + (size_t)nblk * 98304 + s * 16384 + wid * 4096 + lane * 16;
        char* adst = smem + buf * 16384 + wid * 4096;
        char* bdst = smem + 32768 + buf * 16384 + wid * 4096;
        #pragma unroll
        for (int j = 0; j < 4; ++j) {
            gload16(asrc + j * 1024, adst + j * 1024);
            gload16(bsrc + j * 1024, bdst + j * 1024);
        }
    };

    f32x4 acc[4][4] = {};
    auto compute = [&](int buf) {
        const char* ab = smem + buf * 16384;
        const char* bbp = smem + 32768 + buf * 16384;
        #pragma unroll
        for (int c = 0; c < 2; ++c) {
            const int sw = ((c * 4 + g) ^ (r16 & 7)) << 4;
            short8 a[4], bf[4];
            #pragma unroll
            for (int mi = 0; mi < 4; ++mi)
                a[mi] = *(const short8*)(ab + (wm * 64 + mi * 16 + r16) * 128 + sw);
            #pragma unroll
            for (int ni = 0; ni < 4; ++ni)
                bf[ni] = *(const short8*)(bbp + (wn * 64 + ni * 16 + r16) * 128 + sw);
            #pragma unroll
            for (int mi = 0; mi < 4; ++mi)
                #pragma unroll
                for (int ni = 0; ni < 4; ++ni)
                    acc[mi][ni] = MFMA16(a[mi], bf[ni], acc[mi][ni]);
        }
    };

    stage(0, 0);
    for (int s = 0; s < 6; ++s) {
        __syncthreads();
        if (s < 5) stage(s + 1, (s + 1) & 1);
        compute(s & 1);
    }

    float bias[4];
    #pragma unroll
    for (int ni = 0; ni < 4; ++ni) bias[ni] = b_out[nblk * 128 + wn * 64 + ni * 16 + r16];

    #pragma unroll
    for (int mi = 0; mi < 4; ++mi) {
        #pragma unroll
        for (int r = 0; r < 4; ++r) {
            int T = mblk * 128 + wm * 64 + mi * 16 + g * 4 + r;
            int win = T >> 4, tt = T & 15;
            int bb = win >> 8, wh = (win >> 4) & 15, ww = win & 15;
            size_t o = ((size_t)bb * 4096 + (wh * 4 + (tt >> 2)) * 64 + ww * 4 + (tt & 3)) * 384
                     + nblk * 128 + wn * 64;
            #pragma unroll
            for (int ni = 0; ni < 4; ++ni)
                out[o + ni * 16 + r16] = acc[mi][ni][r] + bias[ni];
        }
    }
}

extern "C" void kernel_launch(void* const* d_in, const int* in_sizes, int n_in,
                              void* d_out, int out_size, void* d_ws, size_t ws_size,
                              hipStream_t stream) {
    const float* x     = (const float*)d_in[0];
    const float* w_in  = (const float*)d_in[1];
    const float* b_in  = (const float*)d_in[2];
    const float* w_out = (const float*)d_in[3];
    const float* b_out = (const float*)d_in[4];
    float* out = (float*)d_out;

    char* ws = (char*)d_ws;
    char*  wst = ws + kWstOff;
    char*  wos = ws + kWosOff;
    float* brr = (float*)(ws + kBrrOff);
    char*  att = ws + kAttOff;

    prep<<<dim3(288), dim3(256), 0, stream>>>(w_in, b_in, w_out, wst, wos, brr);
    qkv_attn<<<dim3(6144), dim3(256), 0, stream>>>(x, wst, brr, att);
    out_proj<<<dim3(3072), dim3(256), 0, stream>>>(att, wos, b_out, out);
}

// Round 6
// 286.556 us; speedup vs baseline: 18.3617x; 1.1649x over previous
//
#include <hip/hip_runtime.h>
#include <hip/hip_bf16.h>

typedef __attribute__((ext_vector_type(8))) short short8;
typedef __attribute__((ext_vector_type(4))) float f32x4;

static __device__ __forceinline__ f32x4 MFMA16(short8 a, short8 b, f32x4 c) {
    return __builtin_amdgcn_mfma_f32_16x16x32_bf16(a, b, c, 0, 0, 0);
}
static __device__ __forceinline__ unsigned short f2bf(float f) {
    union { __hip_bfloat16 h; unsigned short u; } c;
    c.h = __float2bfloat16(f);
    return c.u;
}
static __device__ __forceinline__ void gload16(const void* g, void* l) {
    __builtin_amdgcn_global_load_lds(
        (const __attribute__((address_space(1))) unsigned int*)g,
        (__attribute__((address_space(3))) unsigned int*)l, 16, 0, 0);
}

// ---------------- ws layout ----------------
// wst  : bf16, LDS-order pre-swizzled w_in  [6 hp][6 s][1536 granules x16B] @ 0        (884736)
// wos  : bf16, LDS-order pre-swizzled w_out [3 nb][6 s][1024 granules x16B] @ 884736   (294912)
// brr  : f32  [12][96] head-major bias                                      @ 1179648  (4608)
// attst: bf16, LDS-order pre-swizzled att   [1024 mb][6 s][16384 B]         @ 1184256  (100663296)
constexpr size_t kWstOff = 0;
constexpr size_t kWosOff = 884736;
constexpr size_t kBrrOff = 1179648;
constexpr size_t kAttOff = 1184256;

// ================= kernel 0: prep (convert + reorder + pre-swizzle weights) =====
__global__ void prep(const float* __restrict__ w_in, const float* __restrict__ b_in,
                     const float* __restrict__ w_out,
                     char* __restrict__ wst, char* __restrict__ wos,
                     float* __restrict__ brr)
{
    const int i = blockIdx.x * 256 + threadIdx.x;   // grid covers 73728 exactly
    if (i < 55296) {
        int hp = i / 9216, rem = i % 9216;
        int s = rem / 1536, slot16 = rem % 1536;
        int row = slot16 >> 3, sl = slot16 & 7;
        int c8 = sl ^ (row & 7);
        int hh = row / 96, rr = row % 96;
        int sec = rr >> 5, d = rr & 31;
        int srow = sec * 384 + (hp * 2 + hh) * 32 + d;
        int k0 = s * 64 + c8 * 8;
        const float4* src = (const float4*)(w_in + (size_t)srow * 384 + k0);
        float4 a = src[0], b = src[1];
        uint4 w;
        w.x = f2bf(a.x) | ((unsigned)f2bf(a.y) << 16);
        w.y = f2bf(a.z) | ((unsigned)f2bf(a.w) << 16);
        w.z = f2bf(b.x) | ((unsigned)f2bf(b.y) << 16);
        w.w = f2bf(b.z) | ((unsigned)f2bf(b.w) << 16);
        *(uint4*)(wst + (size_t)i * 16) = w;
    } else {
        int j = i - 55296;                           // [0, 18432)
        int nb = j / 6144, rem = j % 6144;
        int s = rem / 1024, slot16 = rem % 1024;
        int row = slot16 >> 3, sl = slot16 & 7;
        int c8 = sl ^ (row & 7);
        int srow = nb * 128 + row;
        int k0 = s * 64 + c8 * 8;
        const float4* src = (const float4*)(w_out + (size_t)srow * 384 + k0);
        float4 a = src[0], b = src[1];
        uint4 w;
        w.x = f2bf(a.x) | ((unsigned)f2bf(a.y) << 16);
        w.y = f2bf(a.z) | ((unsigned)f2bf(a.w) << 16);
        w.z = f2bf(b.x) | ((unsigned)f2bf(b.y) << 16);
        w.w = f2bf(b.z) | ((unsigned)f2bf(b.w) << 16);
        *(uint4*)(wos + (size_t)j * 16) = w;
    }
    if (i < 1152) {
        int h = i / 96, jj = i % 96;
        int sec = jj >> 5, d = jj & 31;
        brr[i] = b_in[sec * 384 + h * 32 + d];
    }
}

// ================= kernel A: QKV projection + window attention =================
// grid: 1024 m-blocks x 6 head-pairs = 6144. block = 512 thr (8 waves).
// BM=128 (8 windows), BN=192 (2 heads x q32|k32|v32), BK=64.
// LDS 80KB: A 2x[128][128B] @0 ; B 2x[192][128B] @32768 -> 2 blocks/CU = 4 waves/SIMD
// attn alias: QKV^T tiles [8 win][2 head][3 sec][32 d][16 t] @0 (48KB)
__global__ __launch_bounds__(512, 2)
void qkv_attn(const float* __restrict__ x, const char* __restrict__ wst,
              const float* __restrict__ brr, char* __restrict__ attst)
{
    __shared__ __align__(16) char smem[81920];

    const int tid  = threadIdx.x;
    const int lane = tid & 63, wid = tid >> 6;         // 8 waves
    const int g = lane >> 4, r16 = lane & 15;
    const int wm = wid >> 1, wn = wid & 1;             // wm 0..3 (M32), wn 0..1 (N96)

    int b = blockIdx.x;
    int L = (b & 7) * 768 + (b >> 3);          // XCD-chunked swizzle (6144 % 8 == 0)
    const int mblk = L / 6, hp = L - mblk * 6;
    const int head = hp * 2 + wn;

    // ---- A staging map: 512 thr cover 128 rows x 64 f32; 4 float4 per thread ----
    const int arow = tid >> 2, aq = tid & 3;           // quarter-row of 16 f32
    int T0 = mblk * 128 + arow;
    int win0 = T0 >> 4, t4 = T0 & 15;
    int bb0 = win0 >> 8, wh = (win0 >> 4) & 15, ww = win0 & 15;
    const float* xrow = x + ((size_t)bb0 * 4096 +
                             (size_t)((wh * 4 + (t4 >> 2)) * 64 + ww * 4 + (t4 & 3))) * 384
                          + aq * 16;

    float4 af[4];
    auto load_A = [&](int s) {
        const float4* xp = (const float4*)(xrow + s * 64);
        #pragma unroll
        for (int j = 0; j < 4; ++j) af[j] = xp[j];
    };
    auto write_A = [&](int buf) {
        #pragma unroll
        for (int j = 0; j < 2; ++j) {
            uint4 w;
            w.x = f2bf(af[2*j].x)   | ((unsigned)f2bf(af[2*j].y)   << 16);
            w.y = f2bf(af[2*j].z)   | ((unsigned)f2bf(af[2*j].w)   << 16);
            w.z = f2bf(af[2*j+1].x) | ((unsigned)f2bf(af[2*j+1].y) << 16);
            w.w = f2bf(af[2*j+1].z) | ((unsigned)f2bf(af[2*j+1].w) << 16);
            int slot = (aq * 2 + j) ^ (arow & 7);
            *(uint4*)(smem + buf * 16384 + arow * 128 + slot * 16) = w;
        }
    };
    const char* wst_blk = wst + (size_t)hp * 147456;
    auto stage_B = [&](int s, int buf) {
        char* dst = smem + 32768 + buf * 24576 + tid * 16;
        const char* src = wst_blk + s * 24576 + tid * 16;
        #pragma unroll
        for (int j = 0; j < 3; ++j) gload16(src + j * 8192, dst + j * 8192);
    };

    f32x4 acc[2][6] = {};
    auto compute = [&](int buf) {
        const char* ab = smem + buf * 16384;
        const char* bbp = smem + 32768 + buf * 24576;
        #pragma unroll
        for (int c = 0; c < 2; ++c) {
            const int sw = ((c * 4 + g) ^ (r16 & 7)) << 4;
            short8 a[2], bf[6];
            #pragma unroll
            for (int mi = 0; mi < 2; ++mi)
                a[mi] = *(const short8*)(ab + (wm * 32 + mi * 16 + r16) * 128 + sw);
            #pragma unroll
            for (int ni = 0; ni < 6; ++ni)
                bf[ni] = *(const short8*)(bbp + (wn * 96 + ni * 16 + r16) * 128 + sw);
            #pragma unroll
            for (int mi = 0; mi < 2; ++mi)
                #pragma unroll
                for (int ni = 0; ni < 6; ++ni)
                    acc[mi][ni] = MFMA16(a[mi], bf[ni], acc[mi][ni]);
        }
    };

    // prologue
    load_A(0);
    stage_B(0, 0);
    write_A(0);
    // main loop: ONE barrier per K-step
    for (int s = 0; s < 6; ++s) {
        __syncthreads();                        // stage_B(s) + write_A(s) visible
        if (s < 5) { load_A(s + 1); stage_B(s + 1, (s + 1) & 1); }
        compute(s & 1);
        if (s < 5) write_A((s + 1) & 1);
    }
    __syncthreads();  // tile-alias region overlaps A bufs / B buf0

    // ---- epilogue: acc (+bias) -> Q^T/K^T/V^T tiles [d][t] ----
    float bias[6];
    #pragma unroll
    for (int ni = 0; ni < 6; ++ni) bias[ni] = brr[head * 96 + ni * 16 + r16];

    #pragma unroll
    for (int mi = 0; mi < 2; ++mi) {
        const int win = wm * 2 + mi;
        #pragma unroll
        for (int ni = 0; ni < 6; ++ni) {
            const int sec = ni >> 1;            // 0=Q 1=K 2=V
            const int d = (ni & 1) * 16 + r16;
            float v0 = acc[mi][ni][0] + bias[ni];
            float v1 = acc[mi][ni][1] + bias[ni];
            float v2 = acc[mi][ni][2] + bias[ni];
            float v3 = acc[mi][ni][3] + bias[ni];
            uint2 w;
            w.x = f2bf(v0) | ((unsigned)f2bf(v1) << 16);
            w.y = f2bf(v2) | ((unsigned)f2bf(v3) << 16);
            *(uint2*)(smem + win * 6144 + wn * 3072 + sec * 1024 + d * 32 + g * 8) = w;
        }
    }

    // ---- attention: 2 windows per wave, zero barriers, P stays in registers ----
    const float kC = 0.17677669529663687f * 1.4426950408889634f;  // (1/sqrt32)*log2e
    const f32x4 zero = {0.f, 0.f, 0.f, 0.f};

    #pragma unroll
    for (int i = 0; i < 2; ++i) {
        const int win = wm * 2 + i;
        const char* base = smem + win * 6144 + wn * 3072;

        union U8 { unsigned short e[8]; short8 v; };
        U8 ku, qu;
        #pragma unroll
        for (int j = 0; j < 8; ++j) {
            const int off = (g * 8 + j) * 32 + r16 * 2;   // elem (d, t=r16)
            qu.e[j] = *(const unsigned short*)(base + off);
            ku.e[j] = *(const unsigned short*)(base + 1024 + off);
        }
        f32x4 s = MFMA16(ku.v, qu.v, zero);     // D[key=4g+r][q=r16]

        float m = fmaxf(fmaxf(s[0], s[1]), fmaxf(s[2], s[3]));
        m = fmaxf(m, __shfl_xor(m, 16, 64));
        m = fmaxf(m, __shfl_xor(m, 32, 64));
        float p[4], sum = 0.f;
        #pragma unroll
        for (int r = 0; r < 4; ++r) { p[r] = exp2f((s[r] - m) * kC); sum += p[r]; }
        sum += __shfl_xor(sum, 16, 64);
        sum += __shfl_xor(sum, 32, 64);
        const float inv = 1.f / sum;

        // P as in-register A-fragment under k-perm k=4g+j (upper 4 elems zero);
        // V's B-fragment uses the SAME key permutation.
        U8 pu;
        pu.e[0] = f2bf(p[0] * inv); pu.e[1] = f2bf(p[1] * inv);
        pu.e[2] = f2bf(p[2] * inv); pu.e[3] = f2bf(p[3] * inv);
        pu.e[4] = 0; pu.e[5] = 0; pu.e[6] = 0; pu.e[7] = 0;

        f32x4 o[2];
        #pragma unroll
        for (int ti = 0; ti < 2; ++ti) {
            U8 vu;                               // V[key=4g+j][d=ti*16+r16]
            *(uint2*)&vu.e[0] = *(const uint2*)(base + 2048 + (ti * 16 + r16) * 32 + g * 8);
            vu.e[4] = 0; vu.e[5] = 0; vu.e[6] = 0; vu.e[7] = 0;
            o[ti] = MFMA16(pu.v, vu.v, zero);    // D[q=4g+r][d-col=r16]
        }
        // store att pre-swizzled for out_proj's global_load_lds staging
        #pragma unroll
        for (int ti = 0; ti < 2; ++ti) {
            #pragma unroll
            for (int r = 0; r < 4; ++r) {
                int row7 = win * 16 + g * 4 + r;
                int col = head * 32 + ti * 16 + r16;
                int sst = col >> 6;
                int sl = ((col >> 3) & 7) ^ (row7 & 7);
                *(unsigned short*)(attst + (size_t)mblk * 98304 + sst * 16384
                                   + row7 * 128 + sl * 16 + (col & 7) * 2)
                    = f2bf(o[ti][r]);
            }
        }
    }
}

// ================= kernel B: out projection =================
// grid: 1024 m-blocks x 3 n-blocks = 3072. BM=128, BN=128, BK=64.
__global__ __launch_bounds__(256, 2)
void out_proj(const char* __restrict__ attst, const char* __restrict__ wos,
              const float* __restrict__ b_out, float* __restrict__ out)
{
    __shared__ __align__(16) char smem[65536];  // A 2x16K @0 ; B 2x16K @32768

    const int tid  = threadIdx.x;
    const int lane = tid & 63, wid = tid >> 6;
    const int g = lane >> 4, r16 = lane & 15;
    const int wm = wid >> 1, wn = wid & 1;

    int b = blockIdx.x;
    int L = (b & 7) * 384 + (b >> 3);
    const int mblk = L / 3, nblk = L - mblk * 3;

    auto stage = [&](int s, int buf) {
        const char* asrc = attst + (size_t)mblk * 98304 + s * 16384 + wid * 4096 + lane * 16;
        const char* bsrc = wos   + (size_t)nblk * 98304 + s * 16384 + wid * 4096 + lane * 16;
        char* adst = smem + buf * 16384 + wid * 4096;
        char* bdst = smem + 32768 + buf * 16384 + wid * 4096;
        #pragma unroll
        for (int j = 0; j < 4; ++j) {
            gload16(asrc + j * 1024, adst + j * 1024);
            gload16(bsrc + j * 1024, bdst + j * 1024);
        }
    };

    f32x4 acc[4][4] = {};
    auto compute = [&](int buf) {
        const char* ab = smem + buf * 16384;
        const char* bbp = smem + 32768 + buf * 16384;
        #pragma unroll
        for (int c = 0; c < 2; ++c) {
            const int sw = ((c * 4 + g) ^ (r16 & 7)) << 4;
            short8 a[4], bf[4];
            #pragma unroll
            for (int mi = 0; mi < 4; ++mi)
                a[mi] = *(const short8*)(ab + (wm * 64 + mi * 16 + r16) * 128 + sw);
            #pragma unroll
            for (int ni = 0; ni < 4; ++ni)
                bf[ni] = *(const short8*)(bbp + (wn * 64 + ni * 16 + r16) * 128 + sw);
            #pragma unroll
            for (int mi = 0; mi < 4; ++mi)
                #pragma unroll
                for (int ni = 0; ni < 4; ++ni)
                    acc[mi][ni] = MFMA16(a[mi], bf[ni], acc[mi][ni]);
        }
    };

    stage(0, 0);
    for (int s = 0; s < 6; ++s) {
        __syncthreads();
        if (s < 5) stage(s + 1, (s + 1) & 1);
        compute(s & 1);
    }

    float bias[4];
    #pragma unroll
    for (int ni = 0; ni < 4; ++ni) bias[ni] = b_out[nblk * 128 + wn * 64 + ni * 16 + r16];

    #pragma unroll
    for (int mi = 0; mi < 4; ++mi) {
        #pragma unroll
        for (int r = 0; r < 4; ++r) {
            int T = mblk * 128 + wm * 64 + mi * 16 + g * 4 + r;
            int win = T >> 4, tt = T & 15;
            int bb = win >> 8, wh = (win >> 4) & 15, ww = win & 15;
            size_t o = ((size_t)bb * 4096 + (wh * 4 + (tt >> 2)) * 64 + ww * 4 + (tt & 3)) * 384
                     + nblk * 128 + wn * 64;
            #pragma unroll
            for (int ni = 0; ni < 4; ++ni)
                out[o + ni * 16 + r16] = acc[mi][ni][r] + bias[ni];
        }
    }
}

extern "C" void kernel_launch(void* const* d_in, const int* in_sizes, int n_in,
                              void* d_out, int out_size, void* d_ws, size_t ws_size,
                              hipStream_t stream) {
    const float* x     = (const float*)d_in[0];
    const float* w_in  = (const float*)d_in[1];
    const float* b_in  = (const float*)d_in[2];
    const float* w_out = (const float*)d_in[3];
    const float* b_out = (const float*)d_in[4];
    float* out = (float*)d_out;

    char* ws = (char*)d_ws;
    char*  wst = ws + kWstOff;
    char*  wos = ws + kWosOff;
    float* brr = (float*)(ws + kBrrOff);
    char*  att = ws + kAttOff;

    prep<<<dim3(288), dim3(256), 0, stream>>>(w_in, b_in, w_out, wst, wos, brr);
    qkv_attn<<<dim3(6144), dim3(512), 0, stream>>>(x, wst, brr, att);
    out_proj<<<dim3(3072), dim3(256), 0, stream>>>(att, wos, b_out, out);
}